// Round 12
// baseline (1993.636 us; speedup 1.0000x reference)
//
#include <hip/hip_runtime.h>

typedef float f32x4v __attribute__((ext_vector_type(4)));
typedef __bf16 bf16x8 __attribute__((ext_vector_type(8)));

__device__ __forceinline__ ushort f2bf(float f) {
    unsigned u = __builtin_bit_cast(unsigned, f);
    return (ushort)((u + 0x7FFFu + ((u >> 16) & 1u)) >> 16);
}

__device__ __forceinline__ void gload16(const void* g, void* l) {
    __builtin_amdgcn_global_load_lds(
        (const __attribute__((address_space(1))) void*)g,
        (__attribute__((address_space(3))) void*)l, 16, 0, 0);
}

// ---------------------------------------------------------------------------
// prep_w: W f32 [K][N] -> Wt bf16 [Npad][K]  (batched over blockIdx.z = layer)
// ---------------------------------------------------------------------------
__global__ __launch_bounds__(256)
void prep_w(const float* __restrict__ Win, ushort* __restrict__ Wout,
            int K, int N, size_t sIn, size_t sOut)
{
    __shared__ float t[64][65];
    const float* W = Win + sIn * blockIdx.z;
    ushort* O = Wout + sOut * blockIdx.z;
    int n0 = blockIdx.x * 64, k0 = blockIdx.y * 64;
    int tid = threadIdx.x;
    int c = tid & 63, r4 = tid >> 6;
#pragma unroll
    for (int i = 0; i < 16; i++) {
        int rr = i * 4 + r4;
        int n = n0 + c;
        t[rr][c] = (n < N) ? W[(size_t)(k0 + rr) * N + n] : 0.f;
    }
    __syncthreads();
#pragma unroll
    for (int i = 0; i < 16; i++) {
        int nr = i * 4 + r4;
        O[(size_t)(n0 + nr) * K + k0 + c] = f2bf(t[c][nr]);
    }
}

// prep_dd: all five 768x768 weight families in one launch. z = wsel*12 + layer
__global__ __launch_bounds__(256)
void prep_dd(const float* __restrict__ W0, const float* __restrict__ W1,
             const float* __restrict__ W2, const float* __restrict__ W3,
             const float* __restrict__ W4,
             ushort* __restrict__ O0, ushort* __restrict__ O1,
             ushort* __restrict__ O2, ushort* __restrict__ O3,
             ushort* __restrict__ O4)
{
    __shared__ float t[64][65];
    const int z = blockIdx.z, wsel = z / 12, l = z % 12;
    const size_t DD = (size_t)768 * 768;
    const float* W = (wsel == 0 ? W0 : wsel == 1 ? W1 : wsel == 2 ? W2 : wsel == 3 ? W3 : W4) + DD * l;
    ushort* O = (wsel == 0 ? O0 : wsel == 1 ? O1 : wsel == 2 ? O2 : wsel == 3 ? O3 : O4) + DD * l;
    int n0 = blockIdx.x * 64, k0 = blockIdx.y * 64;
    int tid = threadIdx.x;
    int c = tid & 63, r4 = tid >> 6;
#pragma unroll
    for (int i = 0; i < 16; i++) {
        int rr = i * 4 + r4;
        t[rr][c] = W[(size_t)(k0 + rr) * 768 + n0 + c];
    }
    __syncthreads();
#pragma unroll
    for (int i = 0; i < 16; i++) {
        int nr = i * 4 + r4;
        O[(size_t)(n0 + nr) * 768 + k0 + c] = f2bf(t[c][nr]);
    }
}

// ---------------------------------------------------------------------------
// GEMM tile body (trunk): C[M,N](+epi) = A[M,K](bf16) * Bt[N,K](bf16)
// BK=64, global_load_lds 16B, double-buffered, XOR swizzle (pre-swizzled src).
// EPI: 0 C=acc ; 1 C+=acc ; 2 Obf=bf16(relu(acc)^2) ; 3 C+=sigmoid(G)*acc
// ---------------------------------------------------------------------------
template <int BM, int BN, int EPI>
__device__ __forceinline__
void gemm_body(const ushort* __restrict__ A, const ushort* __restrict__ B,
               float* __restrict__ C, ushort* __restrict__ Obf,
               const float* __restrict__ G,
               int N, int K, int mtiles, int bid, int tid,
               ushort* __restrict__ As, ushort* __restrict__ Bs)
{
    constexpr int WM = BM / 2, WN = BN / 2, MF = WM / 16, NF = WN / 16;
    const int mt = bid % mtiles, nt = bid / mtiles;
    const int m0 = mt * BM, n0 = nt * BN;
    const int w = tid >> 6, l = tid & 63;
    const int wr = w >> 1, wc = w & 1, g = l >> 4, lr = l & 15;
    const int lrow = l >> 3, lcol = ((l & 7) ^ lrow) * 8;

    auto stage = [&](int buf, int k0) {
#pragma unroll
        for (int i = 0; i < BM / 32; i++) {
            int rb = (i * 4 + w) * 8;
            gload16(A + (size_t)(m0 + rb + lrow) * K + k0 + lcol, &As[buf * BM * 64 + rb * 64]);
        }
#pragma unroll
        for (int i = 0; i < BN / 32; i++) {
            int rb = (i * 4 + w) * 8;
            gload16(B + (size_t)(n0 + rb + lrow) * K + k0 + lcol, &Bs[buf * BN * 64 + rb * 64]);
        }
    };

    f32x4v acc[MF][NF] = {};
    auto comp = [&](int buf) {
#pragma unroll
        for (int kk = 0; kk < 2; kk++) {
            bf16x8 af[MF], bfr[NF];
            const int sl = ((kk * 4 + g) ^ (lr & 7)) * 8;
#pragma unroll
            for (int mi = 0; mi < MF; mi++)
                af[mi] = *(const bf16x8*)&As[buf * BM * 64 + (wr * WM + mi * 16 + lr) * 64 + sl];
#pragma unroll
            for (int ni = 0; ni < NF; ni++)
                bfr[ni] = *(const bf16x8*)&Bs[buf * BN * 64 + (wc * WN + ni * 16 + lr) * 64 + sl];
#pragma unroll
            for (int mi = 0; mi < MF; mi++)
#pragma unroll
                for (int ni = 0; ni < NF; ni++)
                    acc[mi][ni] = __builtin_amdgcn_mfma_f32_16x16x32_bf16(
                        af[mi], bfr[ni], acc[mi][ni], 0, 0, 0);
        }
    };

    const int NS = K >> 6;
    stage(0, 0);
    __syncthreads();
    for (int s = 0; s < NS; s++) {
        if (s + 1 < NS) stage((s + 1) & 1, (s + 1) << 6);
        comp(s & 1);
        __syncthreads();
    }

    // D map: col = lane&15, row = 4*(lane>>4)+q
#pragma unroll
    for (int mi = 0; mi < MF; mi++) {
        int row = m0 + wr * WM + mi * 16 + 4 * g;
#pragma unroll
        for (int ni = 0; ni < NF; ni++) {
            int col = n0 + wc * WN + ni * 16 + lr;
#pragma unroll
            for (int q = 0; q < 4; q++) {
                size_t idx = (size_t)(row + q) * N + col;
                float vv = acc[mi][ni][q];
                if constexpr (EPI == 0) {
                    C[idx] = vv;
                } else if constexpr (EPI == 1) {
                    C[idx] += vv;
                } else if constexpr (EPI == 2) {
                    float t = vv > 0.f ? vv : 0.f;
                    Obf[idx] = f2bf(t * t);
                } else {
                    float gt = 1.f / (1.f + __expf(-G[idx]));
                    C[idx] += gt * vv;
                }
            }
        }
    }
}

template <int BM, int BN, int EPI>
__global__ __launch_bounds__(256)
void gemm2(const ushort* __restrict__ Abase,
           const ushort* __restrict__ B0, const ushort* __restrict__ B1,
           const ushort* __restrict__ B2,
           float* __restrict__ Cbase, ushort* __restrict__ ObfBase,
           const float* __restrict__ Gbase,
           int M, int N, int K, int mtiles)
{
    __shared__ ushort As[2 * BM * 64];
    __shared__ ushort Bs[2 * BN * 64];
    const int z = blockIdx.z;
    const ushort* A = Abase + (size_t)z * M * K;
    const ushort* B = (z == 0) ? B0 : ((z == 1) ? B1 : B2);
    float* C = Cbase ? Cbase + (size_t)z * M * N : nullptr;
    ushort* Obf = ObfBase ? ObfBase + (size_t)z * M * N : nullptr;
    int bid = blockIdx.x;
    { int cpx = gridDim.x >> 3; bid = (bid & 7) * cpx + (bid >> 3); }
    gemm_body<BM, BN, EPI>(A, B, C, Obf, Gbase, N, K, mtiles, bid, threadIdx.x, As, Bs);
}

// merged ck (1536 tiles of 64x32, relu^2->bf16) + cr (384 tiles of 64x32)
__global__ __launch_bounds__(256)
void gemm_ckcr(const ushort* __restrict__ xk, const ushort* __restrict__ xr,
               const ushort* __restrict__ ckT, const ushort* __restrict__ crT,
               ushort* __restrict__ hbuf, float* __restrict__ rrb)
{
    __shared__ ushort As[2 * 64 * 64];
    __shared__ ushort Bs[2 * 32 * 64];
    int bid = blockIdx.x;
    { int cpx = gridDim.x >> 3; bid = (bid & 7) * cpx + (bid >> 3); }  // 1920 % 8 == 0
    if (bid < 1536)
        gemm_body<64, 32, 2>(xk, ckT, nullptr, hbuf, nullptr, 3072, 768, 16,
                             bid, threadIdx.x, As, Bs);
    else
        gemm_body<64, 32, 0>(xr, crT, rrb, nullptr, nullptr, 768, 768, 16,
                             bid - 1536, threadIdx.x, As, Bs);
}

// ---------------------------------------------------------------------------
// head_gemm (round-6 proven version): BM=BN=128, BK=32, 32KB LDS, 4 blk/CU.
// Only change: non-temporal C stores (write-once logits must not thrash L3,
// keeping the 147MB B-panel resident).
// ---------------------------------------------------------------------------
__global__ __launch_bounds__(256, 4)
void head_gemm(const ushort* __restrict__ A, const ushort* __restrict__ B,
               float* __restrict__ C, int M, int N, int K, int mtiles)
{
    constexpr int WM = 64, WN = 64;
    __shared__ ushort As[2][128 * 32];
    __shared__ ushort Bs[2][128 * 32];

    int bid = blockIdx.x;
    { int cpx = gridDim.x >> 3; bid = (bid & 7) * cpx + (bid >> 3); }
    const int mt = bid % mtiles, nt = bid / mtiles;
    const int m0 = mt * 128, n0 = nt * 128;
    const int tid = threadIdx.x, w = tid >> 6, l = tid & 63;
    const int wr = w >> 1, wc = w & 1, g = l >> 4, lr = l & 15;
    const int lrow = l >> 2;                                   // 0..15
    const int lcol = ((l & 3) ^ (lrow & 3) ^ ((lrow >> 2) & 3)) * 8;

    auto stage = [&](int buf, int k0) {
#pragma unroll
        for (int i = 0; i < 2; i++) {
            int rg = i * 4 + w;
            gload16(A + (size_t)(m0 + rg * 16 + lrow) * K + k0 + lcol, &As[buf][rg * 512]);
        }
#pragma unroll
        for (int i = 0; i < 2; i++) {
            int rg = i * 4 + w;
            gload16(B + (size_t)(n0 + rg * 16 + lrow) * K + k0 + lcol, &Bs[buf][rg * 512]);
        }
    };

    f32x4v acc[4][4] = {};
    auto comp = [&](int buf) {
        bf16x8 af[4], bfr[4];
        const int sl = (g ^ (lr & 3) ^ ((lr >> 2) & 3)) * 8;
#pragma unroll
        for (int mi = 0; mi < 4; mi++)
            af[mi] = *(const bf16x8*)&As[buf][(wr * WM + mi * 16 + lr) * 32 + sl];
#pragma unroll
        for (int ni = 0; ni < 4; ni++)
            bfr[ni] = *(const bf16x8*)&Bs[buf][(wc * WN + ni * 16 + lr) * 32 + sl];
#pragma unroll
        for (int mi = 0; mi < 4; mi++)
#pragma unroll
            for (int ni = 0; ni < 4; ni++)
                acc[mi][ni] = __builtin_amdgcn_mfma_f32_16x16x32_bf16(
                    af[mi], bfr[ni], acc[mi][ni], 0, 0, 0);
    };

    const int NS = K / 32;
    stage(0, 0);
    __syncthreads();
    for (int s = 0; s < NS; s++) {
        if (s + 1 < NS) stage((s + 1) & 1, (s + 1) * 32);
        comp(s & 1);
        __syncthreads();
    }

#pragma unroll
    for (int mi = 0; mi < 4; mi++) {
        int row = m0 + wr * WM + mi * 16 + 4 * g;
#pragma unroll
        for (int ni = 0; ni < 4; ni++) {
            int col = n0 + wc * WN + ni * 16 + lr;
            if (col >= N) continue;
#pragma unroll
            for (int q = 0; q < 4; q++)
                __builtin_nontemporal_store(acc[mi][ni][q], &C[(size_t)(row + q) * N + col]);
        }
    }
}

// ---------------------------------------------------------------------------
__device__ __forceinline__ float4 blockReduce4(float4 v) {
#pragma unroll
    for (int off = 32; off; off >>= 1) {
        v.x += __shfl_down(v.x, off);
        v.y += __shfl_down(v.y, off);
        v.z += __shfl_down(v.z, off);
        v.w += __shfl_down(v.w, off);
    }
    __shared__ float4 red[4];
    int tid = threadIdx.x;
    if ((tid & 63) == 0) red[tid >> 6] = v;
    __syncthreads();
    float4 r = red[0];
    r.x += red[1].x + red[2].x + red[3].x;
    r.y += red[1].y + red[2].y + red[3].y;
    r.z += red[1].z + red[2].z + red[3].z;
    r.w += red[1].w + red[2].w + red[3].w;
    return r;
}

__global__ void embed_ln0(const int* __restrict__ tokens, const float* __restrict__ emb,
                          const float* __restrict__ g, const float* __restrict__ be,
                          float* __restrict__ x)
{
    int tau = blockIdx.x, tid = threadIdx.x;
    const float* e = emb + (size_t)tokens[tau] * 768;
    float a[3]; float s1 = 0, s2 = 0;
#pragma unroll
    for (int i = 0; i < 3; i++) {
        float av = e[tid + i * 256]; a[i] = av; s1 += av; s2 += av * av;
    }
    float4 r = blockReduce4(make_float4(s1, s2, 0.f, 0.f));
    const float inv = 1.f / 768.f;
    float m = r.x * inv, va = r.y * inv - m * m, rs = rsqrtf(va + 1e-5f);
#pragma unroll
    for (int i = 0; i < 3; i++) {
        int d = tid + i * 256;
        x[(size_t)tau * 768 + d] = (a[i] - m) * rs * g[d] + be[d];
    }
}

__global__ void ln_mix_tm(const float* __restrict__ x,
                          const float* __restrict__ g, const float* __restrict__ be,
                          const float* __restrict__ muk, const float* __restrict__ muv,
                          const float* __restrict__ mur,
                          ushort* __restrict__ xk, ushort* __restrict__ xv,
                          ushort* __restrict__ xr)
{
    int tau = blockIdx.x, tid = threadIdx.x;
    bool hasp = (tau & 511) != 0;
    const float* xp = x + (size_t)tau * 768;
    const float* pp = xp - 768;
    float a[3], b[3]; float s1 = 0, s2 = 0, s3 = 0, s4 = 0;
#pragma unroll
    for (int i = 0; i < 3; i++) {
        int d = tid + i * 256;
        float av = xp[d]; a[i] = av; s1 += av; s2 += av * av;
        float bv = hasp ? pp[d] : 0.f; b[i] = bv; s3 += bv; s4 += bv * bv;
    }
    float4 r = blockReduce4(make_float4(s1, s2, s3, s4));
    const float inv = 1.f / 768.f;
    float m1 = r.x * inv, va = r.y * inv - m1 * m1, rs1 = rsqrtf(va + 1e-5f);
    float m2 = r.z * inv, vb = r.w * inv - m2 * m2, rs2 = rsqrtf(vb + 1e-5f);
#pragma unroll
    for (int i = 0; i < 3; i++) {
        int d = tid + i * 256;
        float gg = g[d], bb = be[d];
        float xx = (a[i] - m1) * rs1 * gg + bb;
        float sx = hasp ? ((b[i] - m2) * rs2 * gg + bb) : 0.f;
        size_t o = (size_t)tau * 768 + d;
        float mk = muk[d]; xk[o] = f2bf(xx * mk + sx * (1.f - mk));
        float mv = muv[d]; xv[o] = f2bf(xx * mv + sx * (1.f - mv));
        float mr = mur[d]; xr[o] = f2bf(xx * mr + sx * (1.f - mr));
    }
}

__global__ void ln_mix_cm(const float* __restrict__ x,
                          const float* __restrict__ g, const float* __restrict__ be,
                          const float* __restrict__ muk, const float* __restrict__ mur,
                          ushort* __restrict__ xk, ushort* __restrict__ xr)
{
    int tau = blockIdx.x, tid = threadIdx.x;
    bool hasp = (tau & 511) != 0;
    const float* xp = x + (size_t)tau * 768;
    const float* pp = xp - 768;
    float a[3], b[3]; float s1 = 0, s2 = 0, s3 = 0, s4 = 0;
#pragma unroll
    for (int i = 0; i < 3; i++) {
        int d = tid + i * 256;
        float av = xp[d]; a[i] = av; s1 += av; s2 += av * av;
        float bv = hasp ? pp[d] : 0.f; b[i] = bv; s3 += bv; s4 += bv * bv;
    }
    float4 r = blockReduce4(make_float4(s1, s2, s3, s4));
    const float inv = 1.f / 768.f;
    float m1 = r.x * inv, va = r.y * inv - m1 * m1, rs1 = rsqrtf(va + 1e-5f);
    float m2 = r.z * inv, vb = r.w * inv - m2 * m2, rs2 = rsqrtf(vb + 1e-5f);
#pragma unroll
    for (int i = 0; i < 3; i++) {
        int d = tid + i * 256;
        float gg = g[d], bb = be[d];
        float xx = (a[i] - m1) * rs1 * gg + bb;
        float sx = hasp ? ((b[i] - m2) * rs2 * gg + bb) : 0.f;
        size_t o = (size_t)tau * 768 + d;
        float mk = muk[d]; xk[o] = f2bf(xx * mk + sx * (1.f - mk));
        float mr = mur[d]; xr[o] = f2bf(xx * mr + sx * (1.f - mr));
    }
}

__global__ void ln_final(const float* __restrict__ x,
                         const float* __restrict__ g, const float* __restrict__ be,
                         ushort* __restrict__ xf)
{
    int tau = blockIdx.x, tid = threadIdx.x;
    const float* xp = x + (size_t)tau * 768;
    float a[3]; float s1 = 0, s2 = 0;
#pragma unroll
    for (int i = 0; i < 3; i++) {
        float av = xp[tid + i * 256]; a[i] = av; s1 += av; s2 += av * av;
    }
    float4 r = blockReduce4(make_float4(s1, s2, 0.f, 0.f));
    const float inv = 1.f / 768.f;
    float m = r.x * inv, va = r.y * inv - m * m, rs = rsqrtf(va + 1e-5f);
#pragma unroll
    for (int i = 0; i < 3; i++) {
        int d = tid + i * 256;
        xf[(size_t)tau * 768 + d] = f2bf((a[i] - m) * rs * g[d] + be[d]);
    }
}

// ---------------------------------------------------------------------------
// WKV 16-segment parallel scan. Block: 256 thr = 16 channels x 16 segments.
// Grid: B * (768/16) = 96 blocks. Segment length 32.
// ---------------------------------------------------------------------------
__global__ __launch_bounds__(256)
void wkv_par(const float* __restrict__ kk, const float* __restrict__ vv,
             const float* __restrict__ rr, const float* __restrict__ td,
             const float* __restrict__ tf, ushort* __restrict__ out)
{
    const int blk = blockIdx.x, tid = threadIdx.x;
    const int b = blk / 48, chb = blk % 48;
    const int seg = tid >> 4, ch = tid & 15;
    const int d = chb * 16 + ch;
    const size_t base = (size_t)b * 512 * 768 + d;
    const size_t soff = (size_t)seg * 32 * 768;
    const float w = -__expf(td[d]);
    const float u = tf[d];
    const int CH = 8;

    __shared__ float sp[240], sa[240], sb[240];
    __shared__ float pp[256], pa[256], pb[256];

    if (seg < 15) {
        float p = -1e38f, aa = 0.f, bb = 0.f;
        const float* kp = kk + base + soff;
        const float* vp = vv + base + soff;
        float k8[CH], v8[CH], kn[CH], vn[CH];
#pragma unroll
        for (int j = 0; j < CH; j++) { k8[j] = kp[j * 768]; v8[j] = vp[j * 768]; }
        for (int c = 0; c < 32 / CH; c++) {
            if (c + 1 < 32 / CH) {
                size_t o = (size_t)(c + 1) * CH * 768;
#pragma unroll
                for (int j = 0; j < CH; j++) { kn[j] = kp[o + j * 768]; vn[j] = vp[o + j * 768]; }
            }
#pragma unroll
            for (int j = 0; j < CH; j++) {
                float kt = k8[j], vt = v8[j];
                float ww2 = p + w;
                float q2 = fmaxf(ww2, kt);
                float f1 = __expf(ww2 - q2), f2 = __expf(kt - q2);
                aa = f1 * aa + f2 * vt;
                bb = f1 * bb + f2;
                p = q2;
            }
#pragma unroll
            for (int j = 0; j < CH; j++) { k8[j] = kn[j]; v8[j] = vn[j]; }
        }
        sp[seg * 16 + ch] = p; sa[seg * 16 + ch] = aa; sb[seg * 16 + ch] = bb;
    }
    __syncthreads();

    if (tid < 16) {
        const float shift = 32.f * w;
        float P = -1e38f, A = 0.f, Bc = 0.f;
#pragma unroll
        for (int s = 0; s < 16; s++) {
            pp[s * 16 + tid] = P; pa[s * 16 + tid] = A; pb[s * 16 + tid] = Bc;
            if (s < 15) {
                float ps = P + shift;
                float sps = sp[s * 16 + tid];
                float q = fmaxf(ps, sps);
                float e1 = __expf(ps - q), e2 = __expf(sps - q);
                A  = e1 * A  + e2 * sa[s * 16 + tid];
                Bc = e1 * Bc + e2 * sb[s * 16 + tid];
                P = q;
            }
        }
    }
    __syncthreads();

    {
        float p = pp[tid], aa = pa[tid], bb = pb[tid];
        const float* kp = kk + base + soff;
        const float* vp = vv + base + soff;
        const float* rp = rr + base + soff;
        ushort* op = out + base + soff;
        float k8[CH], v8[CH], r8[CH], kn[CH], vn[CH], rn[CH];
#pragma unroll
        for (int j = 0; j < CH; j++) {
            k8[j] = kp[j * 768]; v8[j] = vp[j * 768]; r8[j] = rp[j * 768];
        }
        for (int c = 0; c < 32 / CH; c++) {
            if (c + 1 < 32 / CH) {
                size_t o = (size_t)(c + 1) * CH * 768;
#pragma unroll
                for (int j = 0; j < CH; j++) {
                    kn[j] = kp[o + j * 768]; vn[j] = vp[o + j * 768]; rn[j] = rp[o + j * 768];
                }
            }
#pragma unroll
            for (int j = 0; j < CH; j++) {
                float kt = k8[j], vt = v8[j];
                float ww = u + kt;
                float q = fmaxf(p, ww);
                float e1 = __expf(p - q), e2 = __expf(ww - q);
                float o = (e1 * aa + e2 * vt) / (e1 * bb + e2);
                float sr = 1.f / (1.f + __expf(-r8[j]));
                op[(size_t)(c * CH + j) * 768] = f2bf(sr * o);
                float ww2 = p + w;
                float q2 = fmaxf(ww2, kt);
                float f1 = __expf(ww2 - q2), f2 = __expf(kt - q2);
                aa = f1 * aa + f2 * vt;
                bb = f1 * bb + f2;
                p = q2;
            }
#pragma unroll
            for (int j = 0; j < CH; j++) { k8[j] = kn[j]; v8[j] = vn[j]; r8[j] = rn[j]; }
        }
    }
}

// ---------------------------------------------------------------------------
extern "C" void kernel_launch(void* const* d_in, const int* in_sizes, int n_in,
                              void* d_out, int out_size, void* d_ws, size_t ws_size,
                              hipStream_t stream)
{
    const int V = 100300, D = 768, L = 12, H = 3072;
    const int T = 1024;
    const int Vp = 100352;

    const int*   tokens     = (const int*)d_in[0];
    const float* emb        = (const float*)d_in[1];
    const float* ln0_g      = (const float*)d_in[2];
    const float* ln0_b      = (const float*)d_in[3];
    const float* ln1_g      = (const float*)d_in[4];
    const float* ln1_b      = (const float*)d_in[5];
    const float* ln2_g      = (const float*)d_in[6];
    const float* ln2_b      = (const float*)d_in[7];
    const float* time_decay = (const float*)d_in[8];
    const float* time_first = (const float*)d_in[9];
    const float* tm_mu_k    = (const float*)d_in[10];
    const float* tm_mu_v    = (const float*)d_in[11];
    const float* tm_mu_r    = (const float*)d_in[12];
    const float* tm_Wk      = (const float*)d_in[13];
    const float* tm_Wv      = (const float*)d_in[14];
    const float* tm_Wr      = (const float*)d_in[15];
    const float* tm_Wo      = (const float*)d_in[16];
    const float* cm_mu_k    = (const float*)d_in[17];
    const float* cm_mu_r    = (const float*)d_in[18];
    const float* cm_Wk      = (const float*)d_in[19];
    const float* cm_Wv      = (const float*)d_in[20];
    const float* cm_Wr      = (const float*)d_in[21];
    const float* lnf_g      = (const float*)d_in[22];
    const float* lnf_b      = (const float*)d_in[23];
    const float* head       = (const float*)d_in[24];

    char* wp = (char*)d_ws;
    auto alloc = [&](size_t bytes) -> char* {
        char* p = wp; wp += (bytes + 255) & ~(size_t)255; return p;
    };
    const size_t eDD = (size_t)L * D * D;
    const size_t eDH = (size_t)L * D * H;
    ushort* wkT = (ushort*)alloc(eDD * 2);
    ushort* wvT = (ushort*)alloc(eDD * 2);
    ushort* wrT = (ushort*)alloc(eDD * 2);
    ushort* woT = (ushort*)alloc(eDD * 2);
    ushort* ckT = (ushort*)alloc(eDH * 2);     // [L][H][D]
    ushort* cvT = (ushort*)alloc(eDH * 2);     // [L][D][H]
    ushort* crT = (ushort*)alloc(eDD * 2);
    ushort* hdT = (ushort*)alloc((size_t)Vp * D * 2);

    float*  x    = (float*)alloc((size_t)T * D * 4);
    ushort* xkb  = (ushort*)alloc((size_t)3 * T * D * 2);  // xk, xv, xr
    float*  kvr  = (float*)alloc((size_t)3 * T * D * 4);   // k, v, r
    ushort* rwkv = (ushort*)alloc((size_t)T * D * 2);
    ushort* hbuf = (ushort*)alloc((size_t)T * H * 2);
    float*  rrb  = (float*)alloc((size_t)T * D * 4);
    ushort* xf   = (ushort*)alloc((size_t)T * D * 2);

    // ---- weight prep (transpose + bf16): 4 launches ----
    prep_dd<<<dim3(12, 12, 60), 256, 0, stream>>>(tm_Wk, tm_Wv, tm_Wr, tm_Wo, cm_Wr,
                                                  wkT, wvT, wrT, woT, crT);
    prep_w<<<dim3(H / 64, D / 64, L), 256, 0, stream>>>(cm_Wk, ckT, D, H, (size_t)D * H, (size_t)D * H);
    prep_w<<<dim3(D / 64, H / 64, L), 256, 0, stream>>>(cm_Wv, cvT, H, D, (size_t)D * H, (size_t)D * H);
    prep_w<<<dim3(Vp / 64, D / 64, 1), 256, 0, stream>>>(head, hdT, D, V, 0, 0);

    embed_ln0<<<T, 256, 0, stream>>>(tokens, emb, ln0_g, ln0_b, x);

    for (int l = 0; l < L; l++) {
        ln_mix_tm<<<T, 256, 0, stream>>>(x, ln1_g + l * D, ln1_b + l * D,
                                         tm_mu_k + l * D, tm_mu_v + l * D, tm_mu_r + l * D,
                                         xkb, xkb + (size_t)T * D, xkb + (size_t)2 * T * D);

        gemm2<64, 32, 0><<<dim3(384, 1, 3), 256, 0, stream>>>(
            xkb, wkT + l * (size_t)D * D, wvT + l * (size_t)D * D, wrT + l * (size_t)D * D,
            kvr, nullptr, nullptr, T, D, D, 16);

        wkv_par<<<96, 256, 0, stream>>>(kvr, kvr + (size_t)T * D, kvr + (size_t)2 * T * D,
                                        time_decay + l * D, time_first + l * D, rwkv);

        gemm2<64, 32, 1><<<dim3(384, 1, 1), 256, 0, stream>>>(
            rwkv, woT + l * (size_t)D * D, nullptr, nullptr,
            x, nullptr, nullptr, T, D, D, 16);

        ln_mix_cm<<<T, 256, 0, stream>>>(x, ln2_g + l * D, ln2_b + l * D,
                                         cm_mu_k + l * D, cm_mu_r + l * D,
                                         xkb, xkb + (size_t)T * D);

        gemm_ckcr<<<1920, 256, 0, stream>>>(xkb, xkb + (size_t)T * D,
                                            ckT + l * (size_t)D * H, crT + l * (size_t)D * D,
                                            hbuf, rrb);

        gemm2<64, 32, 3><<<dim3(384, 1, 1), 256, 0, stream>>>(
            hbuf, cvT + l * (size_t)D * H, nullptr, nullptr,
            x, nullptr, rrb, T, D, H, 16);
    }

    ln_final<<<T, 256, 0, stream>>>(x, lnf_g, lnf_b, xf);

    head_gemm<<<8 * (Vp / 128), 256, 0, stream>>>(xf, hdT, (float*)d_out, T, V, D, 8);
}

// Round 13
// 1827.275 us; speedup vs baseline: 1.0910x; 1.0910x over previous
//
#include <hip/hip_runtime.h>

typedef float f32x4v __attribute__((ext_vector_type(4)));
typedef __bf16 bf16x8 __attribute__((ext_vector_type(8)));

__device__ __forceinline__ ushort f2bf(float f) {
    unsigned u = __builtin_bit_cast(unsigned, f);
    return (ushort)((u + 0x7FFFu + ((u >> 16) & 1u)) >> 16);
}

__device__ __forceinline__ void gload16(const void* g, void* l) {
    __builtin_amdgcn_global_load_lds(
        (const __attribute__((address_space(1))) void*)g,
        (__attribute__((address_space(3))) void*)l, 16, 0, 0);
}

// ---------------------------------------------------------------------------
// prep_w: W f32 [K][N] -> Wt bf16 [Npad][K]  (batched over blockIdx.z = layer)
// ---------------------------------------------------------------------------
__global__ __launch_bounds__(256)
void prep_w(const float* __restrict__ Win, ushort* __restrict__ Wout,
            int K, int N, size_t sIn, size_t sOut)
{
    __shared__ float t[64][65];
    const float* W = Win + sIn * blockIdx.z;
    ushort* O = Wout + sOut * blockIdx.z;
    int n0 = blockIdx.x * 64, k0 = blockIdx.y * 64;
    int tid = threadIdx.x;
    int c = tid & 63, r4 = tid >> 6;
#pragma unroll
    for (int i = 0; i < 16; i++) {
        int rr = i * 4 + r4;
        int n = n0 + c;
        t[rr][c] = (n < N) ? W[(size_t)(k0 + rr) * N + n] : 0.f;
    }
    __syncthreads();
#pragma unroll
    for (int i = 0; i < 16; i++) {
        int nr = i * 4 + r4;
        O[(size_t)(n0 + nr) * K + k0 + c] = f2bf(t[c][nr]);
    }
}

// prep_dd: all five 768x768 weight families in one launch. z = wsel*12 + layer
__global__ __launch_bounds__(256)
void prep_dd(const float* __restrict__ W0, const float* __restrict__ W1,
             const float* __restrict__ W2, const float* __restrict__ W3,
             const float* __restrict__ W4,
             ushort* __restrict__ O0, ushort* __restrict__ O1,
             ushort* __restrict__ O2, ushort* __restrict__ O3,
             ushort* __restrict__ O4)
{
    __shared__ float t[64][65];
    const int z = blockIdx.z, wsel = z / 12, l = z % 12;
    const size_t DD = (size_t)768 * 768;
    const float* W = (wsel == 0 ? W0 : wsel == 1 ? W1 : wsel == 2 ? W2 : wsel == 3 ? W3 : W4) + DD * l;
    ushort* O = (wsel == 0 ? O0 : wsel == 1 ? O1 : wsel == 2 ? O2 : wsel == 3 ? O3 : O4) + DD * l;
    int n0 = blockIdx.x * 64, k0 = blockIdx.y * 64;
    int tid = threadIdx.x;
    int c = tid & 63, r4 = tid >> 6;
#pragma unroll
    for (int i = 0; i < 16; i++) {
        int rr = i * 4 + r4;
        t[rr][c] = W[(size_t)(k0 + rr) * 768 + n0 + c];
    }
    __syncthreads();
#pragma unroll
    for (int i = 0; i < 16; i++) {
        int nr = i * 4 + r4;
        O[(size_t)(n0 + nr) * 768 + k0 + c] = f2bf(t[c][nr]);
    }
}

// ---------------------------------------------------------------------------
// GEMM tile body (trunk): C[M,N](+epi) = A[M,K](bf16) * Bt[N,K](bf16)
// BK=64, global_load_lds 16B, double-buffered, XOR swizzle (pre-swizzled src).
// EPI: 0 C=acc ; 1 C+=acc ; 2 Obf=bf16(relu(acc)^2) ; 3 C+=sigmoid(G)*acc
// ---------------------------------------------------------------------------
template <int BM, int BN, int EPI>
__device__ __forceinline__
void gemm_body(const ushort* __restrict__ A, const ushort* __restrict__ B,
               float* __restrict__ C, ushort* __restrict__ Obf,
               const float* __restrict__ G,
               int N, int K, int mtiles, int bid, int tid,
               ushort* __restrict__ As, ushort* __restrict__ Bs)
{
    constexpr int WM = BM / 2, WN = BN / 2, MF = WM / 16, NF = WN / 16;
    const int mt = bid % mtiles, nt = bid / mtiles;
    const int m0 = mt * BM, n0 = nt * BN;
    const int w = tid >> 6, l = tid & 63;
    const int wr = w >> 1, wc = w & 1, g = l >> 4, lr = l & 15;
    const int lrow = l >> 3, lcol = ((l & 7) ^ lrow) * 8;

    auto stage = [&](int buf, int k0) {
#pragma unroll
        for (int i = 0; i < BM / 32; i++) {
            int rb = (i * 4 + w) * 8;
            gload16(A + (size_t)(m0 + rb + lrow) * K + k0 + lcol, &As[buf * BM * 64 + rb * 64]);
        }
#pragma unroll
        for (int i = 0; i < BN / 32; i++) {
            int rb = (i * 4 + w) * 8;
            gload16(B + (size_t)(n0 + rb + lrow) * K + k0 + lcol, &Bs[buf * BN * 64 + rb * 64]);
        }
    };

    f32x4v acc[MF][NF] = {};
    auto comp = [&](int buf) {
#pragma unroll
        for (int kk = 0; kk < 2; kk++) {
            bf16x8 af[MF], bfr[NF];
            const int sl = ((kk * 4 + g) ^ (lr & 7)) * 8;
#pragma unroll
            for (int mi = 0; mi < MF; mi++)
                af[mi] = *(const bf16x8*)&As[buf * BM * 64 + (wr * WM + mi * 16 + lr) * 64 + sl];
#pragma unroll
            for (int ni = 0; ni < NF; ni++)
                bfr[ni] = *(const bf16x8*)&Bs[buf * BN * 64 + (wc * WN + ni * 16 + lr) * 64 + sl];
#pragma unroll
            for (int mi = 0; mi < MF; mi++)
#pragma unroll
                for (int ni = 0; ni < NF; ni++)
                    acc[mi][ni] = __builtin_amdgcn_mfma_f32_16x16x32_bf16(
                        af[mi], bfr[ni], acc[mi][ni], 0, 0, 0);
        }
    };

    const int NS = K >> 6;
    stage(0, 0);
    __syncthreads();
    for (int s = 0; s < NS; s++) {
        if (s + 1 < NS) stage((s + 1) & 1, (s + 1) << 6);
        comp(s & 1);
        __syncthreads();
    }

    // D map: col = lane&15, row = 4*(lane>>4)+q
#pragma unroll
    for (int mi = 0; mi < MF; mi++) {
        int row = m0 + wr * WM + mi * 16 + 4 * g;
#pragma unroll
        for (int ni = 0; ni < NF; ni++) {
            int col = n0 + wc * WN + ni * 16 + lr;
#pragma unroll
            for (int q = 0; q < 4; q++) {
                size_t idx = (size_t)(row + q) * N + col;
                float vv = acc[mi][ni][q];
                if constexpr (EPI == 0) {
                    C[idx] = vv;
                } else if constexpr (EPI == 1) {
                    C[idx] += vv;
                } else if constexpr (EPI == 2) {
                    float t = vv > 0.f ? vv : 0.f;
                    Obf[idx] = f2bf(t * t);
                } else {
                    float gt = 1.f / (1.f + __expf(-G[idx]));
                    C[idx] += gt * vv;
                }
            }
        }
    }
}

template <int BM, int BN, int EPI>
__global__ __launch_bounds__(256)
void gemm2(const ushort* __restrict__ Abase,
           const ushort* __restrict__ B0, const ushort* __restrict__ B1,
           const ushort* __restrict__ B2,
           float* __restrict__ Cbase, ushort* __restrict__ ObfBase,
           const float* __restrict__ Gbase,
           int M, int N, int K, int mtiles)
{
    __shared__ ushort As[2 * BM * 64];
    __shared__ ushort Bs[2 * BN * 64];
    const int z = blockIdx.z;
    const ushort* A = Abase + (size_t)z * M * K;
    const ushort* B = (z == 0) ? B0 : ((z == 1) ? B1 : B2);
    float* C = Cbase ? Cbase + (size_t)z * M * N : nullptr;
    ushort* Obf = ObfBase ? ObfBase + (size_t)z * M * N : nullptr;
    int bid = blockIdx.x;
    { int cpx = gridDim.x >> 3; bid = (bid & 7) * cpx + (bid >> 3); }
    gemm_body<BM, BN, EPI>(A, B, C, Obf, Gbase, N, K, mtiles, bid, threadIdx.x, As, Bs);
}

// merged ck (1536 tiles of 64x32, relu^2->bf16) + cr (384 tiles of 64x32)
__global__ __launch_bounds__(256)
void gemm_ckcr(const ushort* __restrict__ xk, const ushort* __restrict__ xr,
               const ushort* __restrict__ ckT, const ushort* __restrict__ crT,
               ushort* __restrict__ hbuf, float* __restrict__ rrb)
{
    __shared__ ushort As[2 * 64 * 64];
    __shared__ ushort Bs[2 * 32 * 64];
    int bid = blockIdx.x;
    { int cpx = gridDim.x >> 3; bid = (bid & 7) * cpx + (bid >> 3); }  // 1920 % 8 == 0
    if (bid < 1536)
        gemm_body<64, 32, 2>(xk, ckT, nullptr, hbuf, nullptr, 3072, 768, 16,
                             bid, threadIdx.x, As, Bs);
    else
        gemm_body<64, 32, 0>(xr, crT, rrb, nullptr, nullptr, 768, 768, 16,
                             bid - 1536, threadIdx.x, As, Bs);
}

// ---------------------------------------------------------------------------
// head_gemm (round-6 proven version, exact): BM=BN=128, BK=32, 32KB LDS, 4/CU.
// Plain scalar dword C-stores through L2 (measured write-optimal: 427MB).
// ---------------------------------------------------------------------------
__global__ __launch_bounds__(256, 4)
void head_gemm(const ushort* __restrict__ A, const ushort* __restrict__ B,
               float* __restrict__ C, int M, int N, int K, int mtiles)
{
    constexpr int WM = 64, WN = 64;
    __shared__ ushort As[2][128 * 32];
    __shared__ ushort Bs[2][128 * 32];

    int bid = blockIdx.x;
    { int cpx = gridDim.x >> 3; bid = (bid & 7) * cpx + (bid >> 3); }
    const int mt = bid % mtiles, nt = bid / mtiles;
    const int m0 = mt * 128, n0 = nt * 128;
    const int tid = threadIdx.x, w = tid >> 6, l = tid & 63;
    const int wr = w >> 1, wc = w & 1, g = l >> 4, lr = l & 15;
    const int lrow = l >> 2;                                   // 0..15
    const int lcol = ((l & 3) ^ (lrow & 3) ^ ((lrow >> 2) & 3)) * 8;

    auto stage = [&](int buf, int k0) {
#pragma unroll
        for (int i = 0; i < 2; i++) {
            int rg = i * 4 + w;
            gload16(A + (size_t)(m0 + rg * 16 + lrow) * K + k0 + lcol, &As[buf][rg * 512]);
        }
#pragma unroll
        for (int i = 0; i < 2; i++) {
            int rg = i * 4 + w;
            gload16(B + (size_t)(n0 + rg * 16 + lrow) * K + k0 + lcol, &Bs[buf][rg * 512]);
        }
    };

    f32x4v acc[4][4] = {};
    auto comp = [&](int buf) {
        bf16x8 af[4], bfr[4];
        const int sl = (g ^ (lr & 3) ^ ((lr >> 2) & 3)) * 8;
#pragma unroll
        for (int mi = 0; mi < 4; mi++)
            af[mi] = *(const bf16x8*)&As[buf][(wr * WM + mi * 16 + lr) * 32 + sl];
#pragma unroll
        for (int ni = 0; ni < 4; ni++)
            bfr[ni] = *(const bf16x8*)&Bs[buf][(wc * WN + ni * 16 + lr) * 32 + sl];
#pragma unroll
        for (int mi = 0; mi < 4; mi++)
#pragma unroll
            for (int ni = 0; ni < 4; ni++)
                acc[mi][ni] = __builtin_amdgcn_mfma_f32_16x16x32_bf16(
                    af[mi], bfr[ni], acc[mi][ni], 0, 0, 0);
    };

    const int NS = K / 32;
    stage(0, 0);
    __syncthreads();
    for (int s = 0; s < NS; s++) {
        if (s + 1 < NS) stage((s + 1) & 1, (s + 1) * 32);
        comp(s & 1);
        __syncthreads();
    }

#pragma unroll
    for (int mi = 0; mi < 4; mi++) {
        int row = m0 + wr * WM + mi * 16 + 4 * g;
#pragma unroll
        for (int ni = 0; ni < 4; ni++) {
            int col = n0 + wc * WN + ni * 16 + lr;
            if (col >= N) continue;
#pragma unroll
            for (int q = 0; q < 4; q++)
                C[(size_t)(row + q) * N + col] = acc[mi][ni][q];
        }
    }
}

// ---------------------------------------------------------------------------
__device__ __forceinline__ float4 blockReduce4(float4 v) {
#pragma unroll
    for (int off = 32; off; off >>= 1) {
        v.x += __shfl_down(v.x, off);
        v.y += __shfl_down(v.y, off);
        v.z += __shfl_down(v.z, off);
        v.w += __shfl_down(v.w, off);
    }
    __shared__ float4 red[4];
    int tid = threadIdx.x;
    if ((tid & 63) == 0) red[tid >> 6] = v;
    __syncthreads();
    float4 r = red[0];
    r.x += red[1].x + red[2].x + red[3].x;
    r.y += red[1].y + red[2].y + red[3].y;
    r.z += red[1].z + red[2].z + red[3].z;
    r.w += red[1].w + red[2].w + red[3].w;
    return r;
}

__global__ void embed_ln0(const int* __restrict__ tokens, const float* __restrict__ emb,
                          const float* __restrict__ g, const float* __restrict__ be,
                          float* __restrict__ x)
{
    int tau = blockIdx.x, tid = threadIdx.x;
    const float* e = emb + (size_t)tokens[tau] * 768;
    float a[3]; float s1 = 0, s2 = 0;
#pragma unroll
    for (int i = 0; i < 3; i++) {
        float av = e[tid + i * 256]; a[i] = av; s1 += av; s2 += av * av;
    }
    float4 r = blockReduce4(make_float4(s1, s2, 0.f, 0.f));
    const float inv = 1.f / 768.f;
    float m = r.x * inv, va = r.y * inv - m * m, rs = rsqrtf(va + 1e-5f);
#pragma unroll
    for (int i = 0; i < 3; i++) {
        int d = tid + i * 256;
        x[(size_t)tau * 768 + d] = (a[i] - m) * rs * g[d] + be[d];
    }
}

__global__ void ln_mix_tm(const float* __restrict__ x,
                          const float* __restrict__ g, const float* __restrict__ be,
                          const float* __restrict__ muk, const float* __restrict__ muv,
                          const float* __restrict__ mur,
                          ushort* __restrict__ xk, ushort* __restrict__ xv,
                          ushort* __restrict__ xr)
{
    int tau = blockIdx.x, tid = threadIdx.x;
    bool hasp = (tau & 511) != 0;
    const float* xp = x + (size_t)tau * 768;
    const float* pp = xp - 768;
    float a[3], b[3]; float s1 = 0, s2 = 0, s3 = 0, s4 = 0;
#pragma unroll
    for (int i = 0; i < 3; i++) {
        int d = tid + i * 256;
        float av = xp[d]; a[i] = av; s1 += av; s2 += av * av;
        float bv = hasp ? pp[d] : 0.f; b[i] = bv; s3 += bv; s4 += bv * bv;
    }
    float4 r = blockReduce4(make_float4(s1, s2, s3, s4));
    const float inv = 1.f / 768.f;
    float m1 = r.x * inv, va = r.y * inv - m1 * m1, rs1 = rsqrtf(va + 1e-5f);
    float m2 = r.z * inv, vb = r.w * inv - m2 * m2, rs2 = rsqrtf(vb + 1e-5f);
#pragma unroll
    for (int i = 0; i < 3; i++) {
        int d = tid + i * 256;
        float gg = g[d], bb = be[d];
        float xx = (a[i] - m1) * rs1 * gg + bb;
        float sx = hasp ? ((b[i] - m2) * rs2 * gg + bb) : 0.f;
        size_t o = (size_t)tau * 768 + d;
        float mk = muk[d]; xk[o] = f2bf(xx * mk + sx * (1.f - mk));
        float mv = muv[d]; xv[o] = f2bf(xx * mv + sx * (1.f - mv));
        float mr = mur[d]; xr[o] = f2bf(xx * mr + sx * (1.f - mr));
    }
}

__global__ void ln_mix_cm(const float* __restrict__ x,
                          const float* __restrict__ g, const float* __restrict__ be,
                          const float* __restrict__ muk, const float* __restrict__ mur,
                          ushort* __restrict__ xk, ushort* __restrict__ xr)
{
    int tau = blockIdx.x, tid = threadIdx.x;
    bool hasp = (tau & 511) != 0;
    const float* xp = x + (size_t)tau * 768;
    const float* pp = xp - 768;
    float a[3], b[3]; float s1 = 0, s2 = 0, s3 = 0, s4 = 0;
#pragma unroll
    for (int i = 0; i < 3; i++) {
        int d = tid + i * 256;
        float av = xp[d]; a[i] = av; s1 += av; s2 += av * av;
        float bv = hasp ? pp[d] : 0.f; b[i] = bv; s3 += bv; s4 += bv * bv;
    }
    float4 r = blockReduce4(make_float4(s1, s2, s3, s4));
    const float inv = 1.f / 768.f;
    float m1 = r.x * inv, va = r.y * inv - m1 * m1, rs1 = rsqrtf(va + 1e-5f);
    float m2 = r.z * inv, vb = r.w * inv - m2 * m2, rs2 = rsqrtf(vb + 1e-5f);
#pragma unroll
    for (int i = 0; i < 3; i++) {
        int d = tid + i * 256;
        float gg = g[d], bb = be[d];
        float xx = (a[i] - m1) * rs1 * gg + bb;
        float sx = hasp ? ((b[i] - m2) * rs2 * gg + bb) : 0.f;
        size_t o = (size_t)tau * 768 + d;
        float mk = muk[d]; xk[o] = f2bf(xx * mk + sx * (1.f - mk));
        float mr = mur[d]; xr[o] = f2bf(xx * mr + sx * (1.f - mr));
    }
}

__global__ void ln_final(const float* __restrict__ x,
                         const float* __restrict__ g, const float* __restrict__ be,
                         ushort* __restrict__ xf)
{
    int tau = blockIdx.x, tid = threadIdx.x;
    const float* xp = x + (size_t)tau * 768;
    float a[3]; float s1 = 0, s2 = 0;
#pragma unroll
    for (int i = 0; i < 3; i++) {
        float av = xp[tid + i * 256]; a[i] = av; s1 += av; s2 += av * av;
    }
    float4 r = blockReduce4(make_float4(s1, s2, 0.f, 0.f));
    const float inv = 1.f / 768.f;
    float m = r.x * inv, va = r.y * inv - m * m, rs = rsqrtf(va + 1e-5f);
#pragma unroll
    for (int i = 0; i < 3; i++) {
        int d = tid + i * 256;
        xf[(size_t)tau * 768 + d] = f2bf((a[i] - m) * rs * g[d] + be[d]);
    }
}

// ---------------------------------------------------------------------------
// WKV 16-segment parallel scan. Block: 256 thr = 16 channels x 16 segments.
// Grid: B * (768/16) = 96 blocks. Segment length 32.
// ---------------------------------------------------------------------------
__global__ __launch_bounds__(256)
void wkv_par(const float* __restrict__ kk, const float* __restrict__ vv,
             const float* __restrict__ rr, const float* __restrict__ td,
             const float* __restrict__ tf, ushort* __restrict__ out)
{
    const int blk = blockIdx.x, tid = threadIdx.x;
    const int b = blk / 48, chb = blk % 48;
    const int seg = tid >> 4, ch = tid & 15;
    const int d = chb * 16 + ch;
    const size_t base = (size_t)b * 512 * 768 + d;
    const size_t soff = (size_t)seg * 32 * 768;
    const float w = -__expf(td[d]);
    const float u = tf[d];
    const int CH = 8;

    __shared__ float sp[240], sa[240], sb[240];
    __shared__ float pp[256], pa[256], pb[256];

    if (seg < 15) {
        float p = -1e38f, aa = 0.f, bb = 0.f;
        const float* kp = kk + base + soff;
        const float* vp = vv + base + soff;
        float k8[CH], v8[CH], kn[CH], vn[CH];
#pragma unroll
        for (int j = 0; j < CH; j++) { k8[j] = kp[j * 768]; v8[j] = vp[j * 768]; }
        for (int c = 0; c < 32 / CH; c++) {
            if (c + 1 < 32 / CH) {
                size_t o = (size_t)(c + 1) * CH * 768;
#pragma unroll
                for (int j = 0; j < CH; j++) { kn[j] = kp[o + j * 768]; vn[j] = vp[o + j * 768]; }
            }
#pragma unroll
            for (int j = 0; j < CH; j++) {
                float kt = k8[j], vt = v8[j];
                float ww2 = p + w;
                float q2 = fmaxf(ww2, kt);
                float f1 = __expf(ww2 - q2), f2 = __expf(kt - q2);
                aa = f1 * aa + f2 * vt;
                bb = f1 * bb + f2;
                p = q2;
            }
#pragma unroll
            for (int j = 0; j < CH; j++) { k8[j] = kn[j]; v8[j] = vn[j]; }
        }
        sp[seg * 16 + ch] = p; sa[seg * 16 + ch] = aa; sb[seg * 16 + ch] = bb;
    }
    __syncthreads();

    if (tid < 16) {
        const float shift = 32.f * w;
        float P = -1e38f, A = 0.f, Bc = 0.f;
#pragma unroll
        for (int s = 0; s < 16; s++) {
            pp[s * 16 + tid] = P; pa[s * 16 + tid] = A; pb[s * 16 + tid] = Bc;
            if (s < 15) {
                float ps = P + shift;
                float sps = sp[s * 16 + tid];
                float q = fmaxf(ps, sps);
                float e1 = __expf(ps - q), e2 = __expf(sps - q);
                A  = e1 * A  + e2 * sa[s * 16 + tid];
                Bc = e1 * Bc + e2 * sb[s * 16 + tid];
                P = q;
            }
        }
    }
    __syncthreads();

    {
        float p = pp[tid], aa = pa[tid], bb = pb[tid];
        const float* kp = kk + base + soff;
        const float* vp = vv + base + soff;
        const float* rp = rr + base + soff;
        ushort* op = out + base + soff;
        float k8[CH], v8[CH], r8[CH], kn[CH], vn[CH], rn[CH];
#pragma unroll
        for (int j = 0; j < CH; j++) {
            k8[j] = kp[j * 768]; v8[j] = vp[j * 768]; r8[j] = rp[j * 768];
        }
        for (int c = 0; c < 32 / CH; c++) {
            if (c + 1 < 32 / CH) {
                size_t o = (size_t)(c + 1) * CH * 768;
#pragma unroll
                for (int j = 0; j < CH; j++) {
                    kn[j] = kp[o + j * 768]; vn[j] = vp[o + j * 768]; rn[j] = rp[o + j * 768];
                }
            }
#pragma unroll
            for (int j = 0; j < CH; j++) {
                float kt = k8[j], vt = v8[j];
                float ww = u + kt;
                float q = fmaxf(p, ww);
                float e1 = __expf(p - q), e2 = __expf(ww - q);
                float o = (e1 * aa + e2 * vt) / (e1 * bb + e2);
                float sr = 1.f / (1.f + __expf(-r8[j]));
                op[(size_t)(c * CH + j) * 768] = f2bf(sr * o);
                float ww2 = p + w;
                float q2 = fmaxf(ww2, kt);
                float f1 = __expf(ww2 - q2), f2 = __expf(kt - q2);
                aa = f1 * aa + f2 * vt;
                bb = f1 * bb + f2;
                p = q2;
            }
#pragma unroll
            for (int j = 0; j < CH; j++) { k8[j] = kn[j]; v8[j] = vn[j]; r8[j] = rn[j]; }
        }
    }
}

// ---------------------------------------------------------------------------
extern "C" void kernel_launch(void* const* d_in, const int* in_sizes, int n_in,
                              void* d_out, int out_size, void* d_ws, size_t ws_size,
                              hipStream_t stream)
{
    const int V = 100300, D = 768, L = 12, H = 3072;
    const int T = 1024;
    const int Vp = 100352;

    const int*   tokens     = (const int*)d_in[0];
    const float* emb        = (const float*)d_in[1];
    const float* ln0_g      = (const float*)d_in[2];
    const float* ln0_b      = (const float*)d_in[3];
    const float* ln1_g      = (const float*)d_in[4];
    const float* ln1_b      = (const float*)d_in[5];
    const float* ln2_g      = (const float*)d_in[6];
    const float* ln2_b      = (const float*)d_in[7];
    const float* time_decay = (const float*)d_in[8];
    const float* time_first = (const float*)d_in[9];
    const float* tm_mu_k    = (const float*)d_in[10];
    const float* tm_mu_v    = (const float*)d_in[11];
    const float* tm_mu_r    = (const float*)d_in[12];
    const float* tm_Wk      = (const float*)d_in[13];
    const float* tm_Wv      = (const float*)d_in[14];
    const float* tm_Wr      = (const float*)d_in[15];
    const float* tm_Wo      = (const float*)d_in[16];
    const float* cm_mu_k    = (const float*)d_in[17];
    const float* cm_mu_r    = (const float*)d_in[18];
    const float* cm_Wk      = (const float*)d_in[19];
    const float* cm_Wv      = (const float*)d_in[20];
    const float* cm_Wr      = (const float*)d_in[21];
    const float* lnf_g      = (const float*)d_in[22];
    const float* lnf_b      = (const float*)d_in[23];
    const float* head       = (const float*)d_in[24];

    char* wp = (char*)d_ws;
    auto alloc = [&](size_t bytes) -> char* {
        char* p = wp; wp += (bytes + 255) & ~(size_t)255; return p;
    };
    const size_t eDD = (size_t)L * D * D;
    const size_t eDH = (size_t)L * D * H;
    ushort* wkT = (ushort*)alloc(eDD * 2);
    ushort* wvT = (ushort*)alloc(eDD * 2);
    ushort* wrT = (ushort*)alloc(eDD * 2);
    ushort* woT = (ushort*)alloc(eDD * 2);
    ushort* ckT = (ushort*)alloc(eDH * 2);     // [L][H][D]
    ushort* cvT = (ushort*)alloc(eDH * 2);     // [L][D][H]
    ushort* crT = (ushort*)alloc(eDD * 2);
    ushort* hdT = (ushort*)alloc((size_t)Vp * D * 2);

    float*  x    = (float*)alloc((size_t)T * D * 4);
    ushort* xkb  = (ushort*)alloc((size_t)3 * T * D * 2);  // xk, xv, xr
    float*  kvr  = (float*)alloc((size_t)3 * T * D * 4);   // k, v, r
    ushort* rwkv = (ushort*)alloc((size_t)T * D * 2);
    ushort* hbuf = (ushort*)alloc((size_t)T * H * 2);
    float*  rrb  = (float*)alloc((size_t)T * D * 4);
    ushort* xf   = (ushort*)alloc((size_t)T * D * 2);

    // ---- weight prep (transpose + bf16): 4 launches ----
    prep_dd<<<dim3(12, 12, 60), 256, 0, stream>>>(tm_Wk, tm_Wv, tm_Wr, tm_Wo, cm_Wr,
                                                  wkT, wvT, wrT, woT, crT);
    prep_w<<<dim3(H / 64, D / 64, L), 256, 0, stream>>>(cm_Wk, ckT, D, H, (size_t)D * H, (size_t)D * H);
    prep_w<<<dim3(D / 64, H / 64, L), 256, 0, stream>>>(cm_Wv, cvT, H, D, (size_t)D * H, (size_t)D * H);
    prep_w<<<dim3(Vp / 64, D / 64, 1), 256, 0, stream>>>(head, hdT, D, V, 0, 0);

    embed_ln0<<<T, 256, 0, stream>>>(tokens, emb, ln0_g, ln0_b, x);

    for (int l = 0; l < L; l++) {
        ln_mix_tm<<<T, 256, 0, stream>>>(x, ln1_g + l * D, ln1_b + l * D,
                                         tm_mu_k + l * D, tm_mu_v + l * D, tm_mu_r + l * D,
                                         xkb, xkb + (size_t)T * D, xkb + (size_t)2 * T * D);

        gemm2<64, 32, 0><<<dim3(384, 1, 3), 256, 0, stream>>>(
            xkb, wkT + l * (size_t)D * D, wvT + l * (size_t)D * D, wrT + l * (size_t)D * D,
            kvr, nullptr, nullptr, T, D, D, 16);

        wkv_par<<<96, 256, 0, stream>>>(kvr, kvr + (size_t)T * D, kvr + (size_t)2 * T * D,
                                        time_decay + l * D, time_first + l * D, rwkv);

        gemm2<32, 32, 1><<<dim3(768, 1, 1), 256, 0, stream>>>(
            rwkv, woT + l * (size_t)D * D, nullptr, nullptr,
            x, nullptr, nullptr, T, D, D, 32);

        ln_mix_cm<<<T, 256, 0, stream>>>(x, ln2_g + l * D, ln2_b + l * D,
                                         cm_mu_k + l * D, cm_mu_r + l * D,
                                         xkb, xkb + (size_t)T * D);

        gemm_ckcr<<<1920, 256, 0, stream>>>(xkb, xkb + (size_t)T * D,
                                            ckT + l * (size_t)D * H, crT + l * (size_t)D * D,
                                            hbuf, rrb);

        gemm2<32, 32, 3><<<dim3(768, 1, 1), 256, 0, stream>>>(
            hbuf, cvT + l * (size_t)D * H, nullptr, nullptr,
            x, nullptr, rrb, T, D, H, 32);
    }

    ln_final<<<T, 256, 0, stream>>>(x, lnf_g, lnf_b, xf);

    head_gemm<<<8 * (Vp / 128), 256, 0, stream>>>(xf, hdT, (float*)d_out, T, V, D, 8);
}